// Round 14
// baseline (151.397 us; speedup 1.0000x reference)
//
#include <hip/hip_runtime.h>
#include <math.h>

// EnhancedSTGCNLayer: x[T,N,64] -> tconv(k=3)+LN+ReLU+res -> GCNConv(softmax ew, self loops) -> [T,N,128]
#define N_NODES 20000
#define E_EDGES 160000
#define T_STEPS 8
#define C_IN    64
#define C_OUT   128

typedef __bf16 bf16x8 __attribute__((ext_vector_type(8)));
typedef float  f32x4  __attribute__((ext_vector_type(4)));
#define MFMA16(a, b, c) __builtin_amdgcn_mfma_f32_16x16x32_bf16((a), (b), (c), 0, 0, 0)

__device__ __forceinline__ unsigned short f2u(float f) {
  __bf16 b = (__bf16)f;                       // RNE fp32->bf16
  return __builtin_bit_cast(unsigned short, b);
}
__device__ __forceinline__ unsigned int pack2(float lo, float hi) {
  return (unsigned int)f2u(lo) | ((unsigned int)f2u(hi) << 16);
}

// ---------------- reduction helpers ----------------
__device__ __forceinline__ float wredSum(float v) {
#pragma unroll
  for (int d = 32; d > 0; d >>= 1) v += __shfl_xor(v, d, 64);
  return v;
}
__device__ __forceinline__ float wredMax(float v) {
#pragma unroll
  for (int d = 32; d > 0; d >>= 1) v = fmaxf(v, __shfl_xor(v, d, 64));
  return v;
}
__device__ __forceinline__ int wredSumI(int v) {
#pragma unroll
  for (int d = 32; d > 0; d >>= 1) v += __shfl_xor(v, d, 64);
  return v;
}
__device__ __forceinline__ float bredSum(float v, float* sm4) {
  __syncthreads();
  v = wredSum(v);
  const int lane = threadIdx.x & 63, wid = threadIdx.x >> 6;
  if (lane == 0) sm4[wid] = v;
  __syncthreads();
  return sm4[0] + sm4[1] + sm4[2] + sm4[3];
}
__device__ __forceinline__ float bredMax(float v, float* sm4) {
  __syncthreads();
  v = wredMax(v);
  const int lane = threadIdx.x & 63, wid = threadIdx.x >> 6;
  if (lane == 0) sm4[wid] = v;
  __syncthreads();
  return fmaxf(fmaxf(sm4[0], sm4[1]), fmaxf(sm4[2], sm4[3]));
}
__device__ __forceinline__ int bredSumI(int v, int* sm4) {
  __syncthreads();
  v = wredSumI(v);
  const int lane = threadIdx.x & 63, wid = threadIdx.x >> 6;
  if (lane == 0) sm4[wid] = v;
  __syncthreads();
  return sm4[0] + sm4[1] + sm4[2] + sm4[3];
}

// ---------------- merged prep: weight pack + c2 + deg/cnt init + edge-softmax partials ----------------
__global__ __launch_bounds__(256) void k_prep(const float* __restrict__ tconv_w, const float* __restrict__ res_w,
                                              const float* __restrict__ gcn_w, const float* __restrict__ res_b,
                                              const float* __restrict__ ewt,
                                              unsigned int* __restrict__ Bf, float* __restrict__ c2,
                                              float* __restrict__ deg, int* __restrict__ cnt,
                                              float* __restrict__ pm, float* __restrict__ ps) {
  const int gid = blockIdx.x * 256 + threadIdx.x;
  if (gid < N_NODES) { deg[gid] = 1.0f; cnt[gid] = 0; }
  if (gid < 128) {
    float s = 0.f;
    for (int o = 0; o < 128; ++o) s += gcn_w[gid * 128 + o] * res_b[o];
    c2[gid] = s;
  }
  if (gid < 24576) {
    float v0, v1;
    if (gid < 12288) {
      const int reg = gid & 3, l = (gid >> 2) & 63, ct = (gid >> 8) & 7, ks = gid >> 11;
      const int o = ct * 16 + (l & 15);
      const int k0 = ks * 32 + ((l >> 4) & 3) * 8 + reg * 2;
      const int c0 = k0 & 63, tap0 = k0 >> 6;
      const int c1 = (k0 + 1) & 63, tap1 = (k0 + 1) >> 6;
      v0 = tconv_w[o * 192 + c0 * 3 + tap0];
      v1 = tconv_w[o * 192 + c1 * 3 + tap1];
    } else if (gid < 16384) {
      // W2 fragments: W2[q][k] = sum_o gcn_w[q][o] * res_w[o][k]
      const int g = gid - 12288;
      const int reg = g & 3, l = (g >> 2) & 63, ct = (g >> 8) & 7, ks = g >> 11;  // ks 0..1
      const int q = ct * 16 + (l & 15);
      const int k0 = ks * 32 + ((l >> 4) & 3) * 8 + reg * 2;
      float a0 = 0.f, a1 = 0.f;
      for (int o = 0; o < 128; ++o) {
        const float gq = gcn_w[q * 128 + o];
        a0 = fmaf(gq, res_w[o * 64 + k0], a0);
        a1 = fmaf(gq, res_w[o * 64 + k0 + 1], a1);
      }
      v0 = a0; v1 = a1;
    } else {
      const int g = gid - 16384;
      const int reg = g & 3, l = (g >> 2) & 63, ct = (g >> 8) & 7, ks = g >> 11;
      const int o = ct * 16 + (l & 15);
      const int k0 = ks * 32 + ((l >> 4) & 3) * 8 + reg * 2;
      v0 = gcn_w[o * 128 + k0];
      v1 = gcn_w[o * 128 + k0 + 1];
    }
    Bf[gid] = pack2(v0, v1);
  }
  // edge-softmax partials (online max+sum)
  __shared__ float sm4[4];
  float m = -3.4e38f, s = 0.f;
  for (int i = blockIdx.x * 256 + threadIdx.x; i < E_EDGES; i += 256 * 256) {
    const float xw = ewt[i];
    if (xw > m) { s = s * expf(m - xw) + 1.f; m = xw; }
    else        { s += expf(xw - m); }
  }
  const float M = bredMax(m, sm4);
  const float sp = (s > 0.f) ? s * expf(m - M) : 0.f;
  const float S = bredSum(sp, sm4);
  if (threadIdx.x == 0) { pm[blockIdx.x] = M; ps[blockIdx.x] = S; }
}

// per-edge: combine 256 partials -> global (M,S); softmax weight, degree accumulation, in-degree count
__global__ __launch_bounds__(256) void k_edge(const float* __restrict__ w, const int* __restrict__ ei,
                                              const float* __restrict__ pm, const float* __restrict__ ps,
                                              float* __restrict__ ewv, float* __restrict__ deg,
                                              int* __restrict__ cnt) {
  __shared__ float sm4[4];
  const float mloc = pm[threadIdx.x];
  const float mx   = bredMax(mloc, sm4);
  const float sp   = ps[threadIdx.x] * expf(mloc - mx);
  const float sum  = bredSum(sp, sm4);
  const int e = blockIdx.x * 256 + threadIdx.x;  // grid = E/256 exact
  const float v = expf(w[e] - mx) / sum;
  ewv[e] = v;
  const int c = ei[E_EDGES + e];
  atomicAdd(&deg[c], v);
  atomicAdd(&cnt[c], 1);
}

// ---------------- merged CSR scan (dinv + cross-chunk base + intra-chunk scan) ----------------
__global__ __launch_bounds__(256) void k_scan2(const int* __restrict__ cnt, const float* __restrict__ deg,
                                               float* __restrict__ dinv, int* __restrict__ off,
                                               int* __restrict__ cursor) {
  __shared__ int smI[4];
  __shared__ int wpart[4];
  const int tid = threadIdx.x, lane = tid & 63, wid = tid >> 6;
  const int i = blockIdx.x * 256 + tid;
  if (i < N_NODES) dinv[i] = rsqrtf(deg[i]);     // deg >= 1 (self loop)
  int part = 0;
  const int lim = blockIdx.x * 256;
  for (int j = tid; j < lim; j += 256) part += cnt[j];
  const int base = bredSumI(part, smI);
  const int v = (i < N_NODES) ? cnt[i] : 0;
  int s = v;
#pragma unroll
  for (int d = 1; d < 64; d <<= 1) { const int u = __shfl_up(s, d, 64); if (lane >= d) s += u; }
  if (lane == 63) wpart[wid] = s;
  __syncthreads();
  int add = base;
#pragma unroll
  for (int wv = 0; wv < 4; ++wv) if (wv < wid) add += wpart[wv];
  if (i < N_NODES) { const int excl = add + (s - v); off[i] = excl; cursor[i] = excl; }
  if (i == N_NODES - 1) off[N_NODES] = E_EDGES;
}

// per-edge: FULL multiplier (sym-norm x source int8 scale) + CSR scatter by destination
__global__ __launch_bounds__(256) void k_norm_scatter(const int* __restrict__ ei, const float* __restrict__ ewv,
                                                      const float* __restrict__ dinv, const float* __restrict__ qsc,
                                                      int* __restrict__ cursor, uint2* __restrict__ srcnrm) {
  const int e = blockIdx.x * 256 + threadIdx.x;
  const int r = ei[e], c = ei[E_EDGES + e];
  const float mul = dinv[r] * ewv[e] * dinv[c] * qsc[r];  // runs after k_fuse: qsc ready
  const int pos = atomicAdd(&cursor[c], 1);
  srcnrm[pos] = make_uint2((unsigned int)r, __builtin_bit_cast(unsigned int, mul));
}

// ---------------- FUSED node transform + GCN linear -> int8 xq ----------------
// grid 1250; each block loops over 2 groups of 8 nodes (amortizes the 98KB weight-table
// read + block-start latency ramp over 2x the work). 64 rows (row = nn*8+t), 4 waves.
// Residual folded through GCN (W2 = gcn_w@res_w). Per-node max via shfl butterfly (r12/13).
#define XS_NODE 720   // bf16 units per node (10 slots * 72)
#define XS_SLOT 72    // bf16 units per t-slot; 36 dw === 4 (mod 32)
#define AS2_STRIDE 136
__global__ __launch_bounds__(256, 2) void k_fuse(const float* __restrict__ x,
                                                 const float* __restrict__ tconv_b,
                                                 const float* __restrict__ ln_g, const float* __restrict__ ln_b,
                                                 const unsigned int* __restrict__ Bf,
                                                 const float* __restrict__ c2,
                                                 unsigned char* __restrict__ xq,
                                                 float* __restrict__ qsc) {
  const int tid = threadIdx.x, lane = tid & 63, w = tid >> 6;
  const int l15 = lane & 15, lg = lane >> 4;

  __shared__ __align__(16) unsigned short Xs[8 * XS_NODE];        // 11520 B
  __shared__ __align__(16) unsigned short As2[64 * AS2_STRIDE];   // 17408 B
  __shared__ float psum[4][64], psq[4][64];     // 2048 B
  __shared__ float smu[64], srs[64];            // 512 B
  __shared__ float pmax4[4][8];                 // per-wave node maxes
  __shared__ float smax8[8];

  // ---- per-wave B fragments (loaded ONCE, serve both groups) ----
  const uint4* Bf4 = (const uint4*)Bf;
  uint4 Bc[2][6], Bw2[2][2];
#pragma unroll
  for (int ct = 0; ct < 2; ++ct) {
    const int ctg = w * 2 + ct;
#pragma unroll
    for (int ks = 0; ks < 6; ++ks) Bc[ct][ks] = Bf4[(ks * 8 + ctg) * 64 + lane];
#pragma unroll
    for (int ks = 0; ks < 2; ++ks) Bw2[ct][ks] = Bf4[3072 + (ks * 8 + ctg) * 64 + lane];
  }
  float cb[2], gv[2], bv[2], cc[2];
#pragma unroll
  for (int ct = 0; ct < 2; ++ct) {
    const int col = w * 32 + ct * 16 + l15;
    cb[ct] = tconv_b[col]; gv[ct] = ln_g[col]; bv[ct] = ln_b[col]; cc[ct] = c2[col];
  }

  for (int g = 0; g < 2; ++g) {
    const int n0 = blockIdx.x * 16 + g * 8;
    __syncthreads();  // protect Xs/As2/psum reuse: prior group's reads complete before new writes

    // ---- phase 1: stage x -> Xs[node][slot=t+1][c] bf16; zero slots 0 and 9 ----
#pragma unroll
    for (int p = 0; p < 4; ++p) {
      const int chunk = p * 256 + tid;          // 1024 = 8t * 8n * 16 float4
      const int tq = chunk >> 7, nn = (chunk >> 4) & 7, c4 = chunk & 15;
      const float4 v = *(const float4*)(x + ((size_t)tq * N_NODES + n0 + nn) * C_IN + c4 * 4);
      uint2 pk; pk.x = pack2(v.x, v.y); pk.y = pack2(v.z, v.w);
      *(uint2*)&Xs[nn * XS_NODE + (tq + 1) * XS_SLOT + c4 * 4] = pk;
    }
    // zero slots 0 and 9: 8 nodes * 2 slots * 18 uint2 = 288
#pragma unroll
    for (int p = 0; p < 2; ++p) {
      const int i = p * 256 + tid;
      if (i < 288) {
        const int nn = i / 36;
        const int r = i - nn * 36;
        const int sl = (r < 18) ? 0 : 9;
        const int of = ((r < 18) ? r : r - 18) * 4;
        *(uint2*)&Xs[nn * XS_NODE + sl * XS_SLOT + of] = make_uint2(0u, 0u);
      }
    }
    __syncthreads();

    // ---- phase 2: conv MFMA over 4 row-tiles (rows = nn*8 + t, t = l15&7) ----
    f32x4 accC[4][2];
#pragma unroll
    for (int rt = 0; rt < 4; ++rt)
#pragma unroll
      for (int ct = 0; ct < 2; ++ct) accC[rt][ct] = (f32x4)0.f;

#pragma unroll
    for (int ks = 0; ks < 6; ++ks) {
      bf16x8 af[4];
      const int slot = (l15 & 7) + (ks >> 1);   // t + tap (zero slots handle edges)
      const int koff = slot * XS_SLOT + (ks & 1) * 32 + lg * 8;
#pragma unroll
      for (int rt = 0; rt < 4; ++rt) {
        const int node = rt * 2 + (l15 >> 3);
        af[rt] = *(const bf16x8*)&Xs[node * XS_NODE + koff];
      }
#pragma unroll
      for (int rt = 0; rt < 4; ++rt)
#pragma unroll
        for (int ct = 0; ct < 2; ++ct)
          accC[rt][ct] = MFMA16(af[rt], __builtin_bit_cast(bf16x8, Bc[ct][ks]), accC[rt][ct]);
    }

    // ---- LayerNorm stats (C-layout: row16 = lg*4+j, col = w*32+ct*16+l15) ----
#pragma unroll
    for (int rt = 0; rt < 4; ++rt) {
      float s[4], s2[4];
#pragma unroll
      for (int j = 0; j < 4; ++j) {
        const float h0 = accC[rt][0][j] + cb[0];
        const float h1 = accC[rt][1][j] + cb[1];
        accC[rt][0][j] = h0; accC[rt][1][j] = h1;
        s[j] = h0 + h1; s2[j] = h0 * h0 + h1 * h1;
      }
#pragma unroll
      for (int d = 1; d < 16; d <<= 1)
#pragma unroll
        for (int j = 0; j < 4; ++j) { s[j] += __shfl_xor(s[j], d, 64); s2[j] += __shfl_xor(s2[j], d, 64); }
      if (l15 == 0)
#pragma unroll
        for (int j = 0; j < 4; ++j) {
          psum[w][rt * 16 + lg * 4 + j] = s[j];
          psq[w][rt * 16 + lg * 4 + j] = s2[j];
        }
    }
    __syncthreads();
    if (tid < 64) {
      const float S  = psum[0][tid] + psum[1][tid] + psum[2][tid] + psum[3][tid];
      const float S2 = psq[0][tid] + psq[1][tid] + psq[2][tid] + psq[3][tid];
      const float mu = S * (1.f / 128.f);
      const float var = S2 * (1.f / 128.f) - mu * mu;
      smu[tid] = mu; srs[tid] = rsqrtf(var + 1e-5f);
    }
    __syncthreads();

    // ---- apply LN + ReLU -> As2 (bf16, XOR-swizzled cols); residual via W2 in phase 3 ----
#pragma unroll
    for (int rt = 0; rt < 4; ++rt)
#pragma unroll
      for (int j = 0; j < 4; ++j) {
        const int row = rt * 16 + lg * 4 + j;
        const float mu = smu[row], rs = srs[row];
        const int sw = ((row >> 3) & 1) << 4;
#pragma unroll
        for (int ct = 0; ct < 2; ++ct) {
          float xc = (accC[rt][ct][j] - mu) * rs * gv[ct] + bv[ct];
          xc = fmaxf(xc, 0.f);
          const int col = w * 32 + ct * 16 + l15;
          As2[row * AS2_STRIDE + (col ^ sw)] = f2u(xc);
        }
      }
    __syncthreads();

    // ---- phase 3: accG = W2 @ x_mid (from Xs) + gcn_w @ relu(LN) (from As2) ----
    uint4 Bg[2][4];
#pragma unroll
    for (int ct = 0; ct < 2; ++ct)
#pragma unroll
      for (int ks = 0; ks < 4; ++ks) Bg[ct][ks] = Bf4[4096 + (ks * 8 + (w * 2 + ct)) * 64 + lane];

    f32x4 accG[4][2];
#pragma unroll
    for (int rt = 0; rt < 4; ++rt)
#pragma unroll
      for (int ct = 0; ct < 2; ++ct) accG[rt][ct] = (f32x4)0.f;

#pragma unroll
    for (int ks = 0; ks < 2; ++ks) {            // W2 part: middle tap, K=64
      bf16x8 af[4];
      const int koff = ((l15 & 7) + 1) * XS_SLOT + ks * 32 + lg * 8;
#pragma unroll
      for (int rt = 0; rt < 4; ++rt) {
        const int node = rt * 2 + (l15 >> 3);
        af[rt] = *(const bf16x8*)&Xs[node * XS_NODE + koff];
      }
#pragma unroll
      for (int rt = 0; rt < 4; ++rt)
#pragma unroll
        for (int ct = 0; ct < 2; ++ct)
          accG[rt][ct] = MFMA16(af[rt], __builtin_bit_cast(bf16x8, Bw2[ct][ks]), accG[rt][ct]);
    }

    const int swr = ((l15 >> 3) & 1) << 4;
#pragma unroll
    for (int ks = 0; ks < 4; ++ks) {            // gcn part: K=128 from As2
      bf16x8 af[4];
      const int koff = (ks * 32 + lg * 8) ^ swr;
#pragma unroll
      for (int rt = 0; rt < 4; ++rt)
        af[rt] = *(const bf16x8*)&As2[(rt * 16 + l15) * AS2_STRIDE + koff];
#pragma unroll
      for (int rt = 0; rt < 4; ++rt)
#pragma unroll
        for (int ct = 0; ct < 2; ++ct)
          accG[rt][ct] = MFMA16(af[rt], __builtin_bit_cast(bf16x8, Bg[ct][ks]), accG[rt][ct]);
    }

    // ---- add c2, then per-node |max| via shfl butterfly (no LDS atomics) ----
#pragma unroll
    for (int rt = 0; rt < 4; ++rt) {
#pragma unroll
      for (int ct = 0; ct < 2; ++ct)
#pragma unroll
        for (int j = 0; j < 4; ++j) accG[rt][ct][j] += cc[ct];
      float m = 0.f;
#pragma unroll
      for (int ct = 0; ct < 2; ++ct)
#pragma unroll
        for (int j = 0; j < 4; ++j) m = fmaxf(m, fabsf(accG[rt][ct][j]));
      // lanes 0-31 hold node rt*2, lanes 32-63 hold rt*2+1; butterfly stays in-half for d<32
#pragma unroll
      for (int d = 1; d < 32; d <<= 1) m = fmaxf(m, __shfl_xor(m, d, 64));
      if ((lane & 31) == 0) pmax4[w][rt * 2 + (lane >> 5)] = m;
    }
    __syncthreads();
    if (tid < 8) {
      const float mx = fmaxf(fmaxf(pmax4[0][tid], pmax4[1][tid]), fmaxf(pmax4[2][tid], pmax4[3][tid]));
      smax8[tid] = mx;
      qsc[n0 + tid] = mx * (1.f / 127.f);
    }
    __syncthreads();

    // ---- store xq: row64 = rt*16+lg*4+j -> nn = rt*2+(lg>>1), t = (lg&1)*4 + j ----
    const int t0 = (lg & 1) * 4;
#pragma unroll
    for (int rt = 0; rt < 4; ++rt) {
      const int nn = rt * 2 + (lg >> 1);
      const size_t n = (size_t)(n0 + nn);
      const float mx = smax8[nn];
      const float inv = (mx > 0.f) ? 127.f / mx : 0.f;
#pragma unroll
      for (int ct = 0; ct < 2; ++ct) {
        const int col = w * 32 + ct * 16 + l15;
        unsigned int pk8 = 0;
#pragma unroll
        for (int j = 0; j < 4; ++j) {
          const int q = (int)rintf(accG[rt][ct][j] * inv) + 128;  // biased uint8
          pk8 |= ((unsigned int)q) << (8 * j);
        }
        *(unsigned int*)(xq + (n * C_OUT + col) * T_STEPS + t0) = pk8;
      }
    }
  }
}

// ---------------- CSR aggregation + bias + ReLU -> out[T,N,128] ----------------
// 2 dests/block, 2 waves/dest (one per 64-channel half)
__global__ __launch_bounds__(256) void k_agg(const unsigned char* __restrict__ xq,
                                             const float* __restrict__ qsc,
                                             const uint2* __restrict__ srcnrm,
                                             const int* __restrict__ off, const float* __restrict__ dinv,
                                             const float* __restrict__ gcn_b, float* __restrict__ out) {
  const int tid = threadIdx.x, lane = tid & 63, w = tid >> 6;
  const int j = blockIdx.x * 2 + (w >> 1);      // grid 10000 exact
  const int ch = (w & 1) * 64 + lane;           // this wave's channel
  const int s = off[j], e = off[j + 1];
  const float d2 = dinv[j] * dinv[j];

  float acc[8];
#pragma unroll
  for (int t = 0; t < 8; ++t) acc[t] = 0.f;

  float summul;
  {
    const float mul = d2 * qsc[j];              // self term as degenerate edge
    summul = mul;
    const uint2 q = *(const uint2*)(xq + ((size_t)j * C_OUT + ch) * T_STEPS);
#pragma unroll
    for (int tt = 0; tt < 4; ++tt) {
      acc[tt]     = fmaf((float)((q.x >> (8 * tt)) & 0xffu), mul, acc[tt]);
      acc[4 + tt] = fmaf((float)((q.y >> (8 * tt)) & 0xffu), mul, acc[4 + tt]);
    }
  }

  for (int k = s; k < e; ++k) {
    const uint2 sn = srcnrm[k];                  // wave-uniform; mul includes qsc[src]
    const int r = (int)sn.x;
    const float mul = __builtin_bit_cast(float, sn.y);
    summul += mul;
    const uint2 q = *(const uint2*)(xq + ((size_t)r * C_OUT + ch) * T_STEPS);
#pragma unroll
    for (int tt = 0; tt < 4; ++tt) {
      acc[tt]     = fmaf((float)((q.x >> (8 * tt)) & 0xffu), mul, acc[tt]);
      acc[4 + tt] = fmaf((float)((q.y >> (8 * tt)) & 0xffu), mul, acc[4 + tt]);
    }
  }

  const float corr = 128.f * summul;             // biased-uint8 correction (incl. self)
  const float b = gcn_b[ch];
#pragma unroll
  for (int t = 0; t < 8; ++t) {
    const float v = acc[t] - corr + b;
    out[((size_t)t * N_NODES + j) * C_OUT + ch] = fmaxf(v, 0.f);
  }
}

// ---------------- host ----------------
extern "C" void kernel_launch(void* const* d_in, const int* in_sizes, int n_in,
                              void* d_out, int out_size, void* d_ws, size_t ws_size,
                              hipStream_t stream) {
  (void)in_sizes; (void)n_in; (void)out_size; (void)ws_size;
  const float* x       = (const float*)d_in[0];
  const int*   ei      = (const int*)d_in[1];
  const float* ewt     = (const float*)d_in[2];
  const float* tconv_w = (const float*)d_in[3];
  const float* tconv_b = (const float*)d_in[4];
  const float* ln_g    = (const float*)d_in[5];
  const float* ln_b    = (const float*)d_in[6];
  const float* res_w   = (const float*)d_in[7];
  const float* res_b   = (const float*)d_in[8];
  const float* gcn_w   = (const float*)d_in[9];
  const float* gcn_b   = (const float*)d_in[10];
  float* out = (float*)d_out;

  // workspace carve (~24 MB)
  unsigned char* xq = (unsigned char*)d_ws;                         // N*128*8 u8 = 20.48 MB
  float* qsc  = (float*)(xq + (size_t)N_NODES * C_OUT * T_STEPS);   // N
  float* c2   = qsc + N_NODES;                                      // 128
  unsigned int* Bf = (unsigned int*)(c2 + 128);                     // 24576 u32
  float* ewv   = (float*)(Bf + 24576);                              // E
  float* deg   = ewv + E_EDGES;                                     // N
  float* dinv  = deg + N_NODES;                                     // N
  float* pm    = dinv + N_NODES;                                    // 256
  float* ps    = pm + 256;                                          // 256
  int*   cnt    = (int*)(ps + 256);                                 // N
  int*   off    = cnt + N_NODES;                                    // N+1
  int*   cursor = off + N_NODES + 1;                                // N
  uint2* srcnrm = (uint2*)(((size_t)(cursor + N_NODES) + 15) & ~(size_t)15);  // E * 8B

  const int nblk = (N_NODES + 255) / 256;                           // 79
  const int eblk = E_EDGES / 256;                                   // 625 exact

  k_prep<<<256, 256, 0, stream>>>(tconv_w, res_w, gcn_w, res_b, ewt, Bf, c2, deg, cnt, pm, ps);
  k_edge<<<eblk, 256, 0, stream>>>(ewt, ei, pm, ps, ewv, deg, cnt);
  k_scan2<<<nblk, 256, 0, stream>>>(cnt, deg, dinv, off, cursor);
  k_fuse<<<1250, 256, 0, stream>>>(x, tconv_b, ln_g, ln_b, Bf, c2, xq, qsc);
  k_norm_scatter<<<eblk, 256, 0, stream>>>(ei, ewv, dinv, qsc, cursor, srcnrm);
  k_agg<<<N_NODES / 2, 256, 0, stream>>>(xq, qsc, srcnrm, off, dinv, gcn_b, out);
}

// Round 15
// 133.174 us; speedup vs baseline: 1.1368x; 1.1368x over previous
//
#include <hip/hip_runtime.h>
#include <math.h>

// EnhancedSTGCNLayer: x[T,N,64] -> tconv(k=3)+LN+ReLU+res -> GCNConv(softmax ew, self loops) -> [T,N,128]
#define N_NODES 20000
#define E_EDGES 160000
#define T_STEPS 8
#define C_IN    64
#define C_OUT   128

typedef __bf16 bf16x8 __attribute__((ext_vector_type(8)));
typedef float  f32x4  __attribute__((ext_vector_type(4)));
#define MFMA16(a, b, c) __builtin_amdgcn_mfma_f32_16x16x32_bf16((a), (b), (c), 0, 0, 0)

__device__ __forceinline__ unsigned short f2u(float f) {
  __bf16 b = (__bf16)f;                       // RNE fp32->bf16
  return __builtin_bit_cast(unsigned short, b);
}
__device__ __forceinline__ unsigned int pack2(float lo, float hi) {
  return (unsigned int)f2u(lo) | ((unsigned int)f2u(hi) << 16);
}

// ---------------- reduction helpers ----------------
__device__ __forceinline__ float wredSum(float v) {
#pragma unroll
  for (int d = 32; d > 0; d >>= 1) v += __shfl_xor(v, d, 64);
  return v;
}
__device__ __forceinline__ float wredMax(float v) {
#pragma unroll
  for (int d = 32; d > 0; d >>= 1) v = fmaxf(v, __shfl_xor(v, d, 64));
  return v;
}
__device__ __forceinline__ int wredSumI(int v) {
#pragma unroll
  for (int d = 32; d > 0; d >>= 1) v += __shfl_xor(v, d, 64);
  return v;
}
__device__ __forceinline__ float bredSum(float v, float* sm4) {
  __syncthreads();
  v = wredSum(v);
  const int lane = threadIdx.x & 63, wid = threadIdx.x >> 6;
  if (lane == 0) sm4[wid] = v;
  __syncthreads();
  return sm4[0] + sm4[1] + sm4[2] + sm4[3];
}
__device__ __forceinline__ float bredMax(float v, float* sm4) {
  __syncthreads();
  v = wredMax(v);
  const int lane = threadIdx.x & 63, wid = threadIdx.x >> 6;
  if (lane == 0) sm4[wid] = v;
  __syncthreads();
  return fmaxf(fmaxf(sm4[0], sm4[1]), fmaxf(sm4[2], sm4[3]));
}
__device__ __forceinline__ int bredSumI(int v, int* sm4) {
  __syncthreads();
  v = wredSumI(v);
  const int lane = threadIdx.x & 63, wid = threadIdx.x >> 6;
  if (lane == 0) sm4[wid] = v;
  __syncthreads();
  return sm4[0] + sm4[1] + sm4[2] + sm4[3];
}

// ---------------- fused edge-weight softmax partials (online max+sum per block) ----------------
__global__ __launch_bounds__(256) void k_esoft(const float* __restrict__ w,
                                               float* __restrict__ pm, float* __restrict__ ps) {
  __shared__ float sm4[4];
  float m = -3.4e38f, s = 0.f;
  for (int i = blockIdx.x * 256 + threadIdx.x; i < E_EDGES; i += 256 * 256) {
    const float xw = w[i];
    if (xw > m) { s = s * expf(m - xw) + 1.f; m = xw; }
    else        { s += expf(xw - m); }
  }
  const float M = bredMax(m, sm4);
  const float sp = (s > 0.f) ? s * expf(m - M) : 0.f;
  const float S = bredSum(sp, sm4);
  if (threadIdx.x == 0) { pm[blockIdx.x] = M; ps[blockIdx.x] = S; }
}

// per-edge: combine 256 partials -> global (M,S); softmax weight, degree accumulation, in-degree count
__global__ __launch_bounds__(256) void k_edge(const float* __restrict__ w, const int* __restrict__ ei,
                                              const float* __restrict__ pm, const float* __restrict__ ps,
                                              float* __restrict__ ewv, float* __restrict__ deg,
                                              int* __restrict__ cnt) {
  __shared__ float sm4[4];
  const float mloc = pm[threadIdx.x];
  const float mx   = bredMax(mloc, sm4);
  const float sp   = ps[threadIdx.x] * expf(mloc - mx);
  const float sum  = bredSum(sp, sm4);
  const int e = blockIdx.x * 256 + threadIdx.x;  // grid = E/256 exact
  const float v = expf(w[e] - mx) / sum;
  ewv[e] = v;
  const int c = ei[E_EDGES + e];
  atomicAdd(&deg[c], v);
  atomicAdd(&cnt[c], 1);
}

// ---------------- parallel CSR scan (2 kernels; chunk-combine folded into scanC) ----------------
__global__ __launch_bounds__(256) void k_scanA(const int* __restrict__ cnt, const float* __restrict__ deg,
                                               float* __restrict__ dinv, int* __restrict__ csum) {
  __shared__ int sm4[4];
  const int i = blockIdx.x * 256 + threadIdx.x;
  const int v = (i < N_NODES) ? cnt[i] : 0;
  if (i < N_NODES) dinv[i] = rsqrtf(deg[i]);  // deg >= 1 (self loop)
  int s = wredSumI(v);
  const int lane = threadIdx.x & 63, wid = threadIdx.x >> 6;
  if (lane == 0) sm4[wid] = s;
  __syncthreads();
  if (threadIdx.x == 0) csum[blockIdx.x] = sm4[0] + sm4[1] + sm4[2] + sm4[3];
}

__global__ __launch_bounds__(256) void k_scanC(const int* __restrict__ cnt, const int* __restrict__ csum,
                                               int* __restrict__ off, int* __restrict__ cursor) {
  __shared__ int smI[4];
  __shared__ int wpart[4];
  const int tid = threadIdx.x, lane = tid & 63, wid = tid >> 6;
  const int nchunk = (N_NODES + 255) / 256;      // 79
  // base = sum of csum[j] for j < blockIdx.x (each block re-reduces the 79 chunk sums)
  const int vb = (tid < nchunk && tid < blockIdx.x) ? csum[tid] : 0;
  const int base = bredSumI(vb, smI);
  const int i = blockIdx.x * 256 + tid;
  const int v = (i < N_NODES) ? cnt[i] : 0;
  int s = v;  // inclusive wave scan
#pragma unroll
  for (int d = 1; d < 64; d <<= 1) { const int u = __shfl_up(s, d, 64); if (lane >= d) s += u; }
  if (lane == 63) wpart[wid] = s;
  __syncthreads();
  int add = base;
#pragma unroll
  for (int wv = 0; wv < 4; ++wv) if (wv < wid) add += wpart[wv];
  if (i < N_NODES) { const int excl = add + (s - v); off[i] = excl; cursor[i] = excl; }
  if (i == N_NODES - 1) off[N_NODES] = E_EDGES;
}

__global__ __launch_bounds__(256) void k_norm_scatter(const int* __restrict__ ei, const float* __restrict__ ewv,
                                                      const float* __restrict__ dinv, int* __restrict__ cursor,
                                                      uint2* __restrict__ srcnrm) {
  const int e = blockIdx.x * 256 + threadIdx.x;
  const int r = ei[e], c = ei[E_EDGES + e];
  const float nm = dinv[r] * ewv[e] * dinv[c];
  const int pos = atomicAdd(&cursor[c], 1);
  srcnrm[pos] = make_uint2((unsigned int)r, __builtin_bit_cast(unsigned int, nm));
}

// ---------------- weight prep (+ fused deg/cnt init) ----------------
__global__ __launch_bounds__(256) void k_wprep(const float* __restrict__ tconv_w, const float* __restrict__ res_w,
                                               const float* __restrict__ gcn_w, unsigned int* __restrict__ Bf,
                                               float* __restrict__ deg, int* __restrict__ cnt) {
  const int gid = blockIdx.x * 256 + threadIdx.x;  // 96 blocks * 256 = 24576 exact
  if (gid < N_NODES) { deg[gid] = 1.0f; cnt[gid] = 0; }
  float v0, v1;
  if (gid < 12288) {
    const int reg = gid & 3, l = (gid >> 2) & 63, ct = (gid >> 8) & 7, ks = gid >> 11;
    const int o = ct * 16 + (l & 15);
    const int k0 = ks * 32 + ((l >> 4) & 3) * 8 + reg * 2;
    const int c0 = k0 & 63, tap0 = k0 >> 6;
    const int c1 = (k0 + 1) & 63, tap1 = (k0 + 1) >> 6;
    v0 = tconv_w[o * 192 + c0 * 3 + tap0];
    v1 = tconv_w[o * 192 + c1 * 3 + tap1];
  } else if (gid < 16384) {
    const int g = gid - 12288;
    const int reg = g & 3, l = (g >> 2) & 63, ct = (g >> 8) & 7, ks = g >> 11;
    const int o = ct * 16 + (l & 15);
    const int k0 = ks * 32 + ((l >> 4) & 3) * 8 + reg * 2;
    v0 = res_w[o * 64 + k0];
    v1 = res_w[o * 64 + k0 + 1];
  } else {
    const int g = gid - 16384;
    const int reg = g & 3, l = (g >> 2) & 63, ct = (g >> 8) & 7, ks = g >> 11;
    const int o = ct * 16 + (l & 15);
    const int k0 = ks * 32 + ((l >> 4) & 3) * 8 + reg * 2;
    v0 = gcn_w[o * 128 + k0];
    v1 = gcn_w[o * 128 + k0 + 1];
  }
  Bf[gid] = pack2(v0, v1);
}

// ---------------- FUSED node transform + GCN linear -> int8 xq only ----------------
// block = 16 nodes x 8 t = 128 output rows (row = nn*8 + t), 256 threads = 4 waves, grid 1250.
// R10 configuration (best measured total) + r13's shfl-butterfly per-node max
// (removes the LDS atomicMax that caused 5.04M SQ_LDS_BANK_CONFLICT = ~4032 serialized
// conflict-cycles/block). launch_bounds(256,2): VGPR cap 128 (r8: arg=3 spills the accs).
#define XS_NODE 720   // bf16 units per node (10 slots * 72)
#define XS_SLOT 72    // bf16 units per t-slot; 36 dw === 4 (mod 32)
#define AS2_STRIDE 136
__global__ __launch_bounds__(256, 2) void k_fuse(const float* __restrict__ x,
                                                 const float* __restrict__ tconv_b,
                                                 const float* __restrict__ ln_g, const float* __restrict__ ln_b,
                                                 const float* __restrict__ res_b,
                                                 const unsigned int* __restrict__ Bf,
                                                 unsigned char* __restrict__ xq,
                                                 float* __restrict__ qsc) {
  const int tid = threadIdx.x, lane = tid & 63, w = tid >> 6;
  const int l15 = lane & 15, lg = lane >> 4;
  const int n0 = blockIdx.x * 16;               // grid = 1250 exact

  // Xs (23040 B) and As2 (34816 B) are time-disjoint (two barriers apart) -> union.
  __shared__ __align__(16) unsigned short XsAs[128 * AS2_STRIDE];  // 34816 B
  unsigned short* Xs  = XsAs;
  unsigned short* As2 = XsAs;
  __shared__ float psum[4][128], psq[4][128];   // 4096 B
  __shared__ float smu[128], srs[128];          // 1024 B
  __shared__ float pmax4[4][16];                // per-wave node maxes (butterfly output)
  __shared__ float smax16[16];

  // ---- phase 1: stage x -> Xs[node][slot=t+1][c] bf16; zero slots 0 and 9 ----
#pragma unroll
  for (int p = 0; p < 8; ++p) {
    const int chunk = p * 256 + tid;            // 2048 = 8t * 16n * 16 float4
    const int tq = chunk >> 8, nn = (chunk >> 4) & 15, c4 = chunk & 15;
    const float4 v = *(const float4*)(x + ((size_t)tq * N_NODES + n0 + nn) * C_IN + c4 * 4);
    uint2 pk; pk.x = pack2(v.x, v.y); pk.y = pack2(v.z, v.w);
    *(uint2*)&Xs[nn * XS_NODE + (tq + 1) * XS_SLOT + c4 * 4] = pk;
  }
  // zero slots 0 and 9: 16 nodes * 2 slots * 18 uint2 = 576
#pragma unroll
  for (int p = 0; p < 3; ++p) {
    const int i = p * 256 + tid;
    if (i < 576) {
      const int nn = i / 36;
      const int r = i - nn * 36;
      const int sl = (r < 18) ? 0 : 9;
      const int of = ((r < 18) ? r : r - 18) * 4;
      *(uint2*)&Xs[nn * XS_NODE + sl * XS_SLOT + of] = make_uint2(0u, 0u);
    }
  }

  // ---- per-wave B fragments: conv + residual ----
  const uint4* Bf4 = (const uint4*)Bf;
  uint4 Bc[2][6], Br[2][2];
#pragma unroll
  for (int ct = 0; ct < 2; ++ct) {
    const int ctg = w * 2 + ct;
#pragma unroll
    for (int ks = 0; ks < 6; ++ks) Bc[ct][ks] = Bf4[(ks * 8 + ctg) * 64 + lane];
#pragma unroll
    for (int ks = 0; ks < 2; ++ks) Br[ct][ks] = Bf4[3072 + (ks * 8 + ctg) * 64 + lane];
  }
  float cb[2], rb[2], gv[2], bv[2];
#pragma unroll
  for (int ct = 0; ct < 2; ++ct) {
    const int col = w * 32 + ct * 16 + l15;
    cb[ct] = tconv_b[col]; rb[ct] = res_b[col]; gv[ct] = ln_g[col]; bv[ct] = ln_b[col];
  }
  __syncthreads();

  // ---- phase 2: conv + res MFMA over 8 row-tiles (rows = nn*8 + t, t = l15&7) ----
  f32x4 accC[8][2], accR[8][2];
#pragma unroll
  for (int rt = 0; rt < 8; ++rt)
#pragma unroll
    for (int ct = 0; ct < 2; ++ct) { accC[rt][ct] = (f32x4)0.f; accR[rt][ct] = (f32x4)0.f; }

#pragma unroll
  for (int ks = 0; ks < 6; ++ks) {
    bf16x8 af[8];
    const int slot = (l15 & 7) + (ks >> 1);   // t + tap (zero slots handle edges)
    const int koff = slot * XS_SLOT + (ks & 1) * 32 + lg * 8;
#pragma unroll
    for (int rt = 0; rt < 8; ++rt) {
      const int node = rt * 2 + (l15 >> 3);
      af[rt] = *(const bf16x8*)&Xs[node * XS_NODE + koff];
    }
#pragma unroll
    for (int rt = 0; rt < 8; ++rt)
#pragma unroll
      for (int ct = 0; ct < 2; ++ct)
        accC[rt][ct] = MFMA16(af[rt], __builtin_bit_cast(bf16x8, Bc[ct][ks]), accC[rt][ct]);
    if (ks == 2 || ks == 3) {                 // middle tap drives the 1x1 residual conv
#pragma unroll
      for (int rt = 0; rt < 8; ++rt)
#pragma unroll
        for (int ct = 0; ct < 2; ++ct)
          accR[rt][ct] = MFMA16(af[rt], __builtin_bit_cast(bf16x8, Br[ct][ks - 2]), accR[rt][ct]);
    }
  }

  // ---- LayerNorm stats (C-layout: row16 = lg*4+j, col = w*32+ct*16+l15) ----
#pragma unroll
  for (int rt = 0; rt < 8; ++rt) {
    float s[4], s2[4];
#pragma unroll
    for (int j = 0; j < 4; ++j) {
      const float h0 = accC[rt][0][j] + cb[0];
      const float h1 = accC[rt][1][j] + cb[1];
      accC[rt][0][j] = h0; accC[rt][1][j] = h1;
      s[j] = h0 + h1; s2[j] = h0 * h0 + h1 * h1;
    }
#pragma unroll
    for (int d = 1; d < 16; d <<= 1)
#pragma unroll
      for (int j = 0; j < 4; ++j) { s[j] += __shfl_xor(s[j], d, 64); s2[j] += __shfl_xor(s2[j], d, 64); }
    if (l15 == 0)
#pragma unroll
      for (int j = 0; j < 4; ++j) {
        psum[w][rt * 16 + lg * 4 + j] = s[j];
        psq[w][rt * 16 + lg * 4 + j] = s2[j];
      }
  }
  __syncthreads();                               // Xs reads done; psum complete
  if (tid < 128) {
    const float S  = psum[0][tid] + psum[1][tid] + psum[2][tid] + psum[3][tid];
    const float S2 = psq[0][tid] + psq[1][tid] + psq[2][tid] + psq[3][tid];
    const float mu = S * (1.f / 128.f);
    const float var = S2 * (1.f / 128.f) - mu * mu;
    smu[tid] = mu; srs[tid] = rsqrtf(var + 1e-5f);
  }
  __syncthreads();                               // safe to overwrite Xs region with As2

  // ---- apply LN + ReLU + residual -> As2 (bf16, XOR-swizzled cols) ----
#pragma unroll
  for (int rt = 0; rt < 8; ++rt)
#pragma unroll
    for (int j = 0; j < 4; ++j) {
      const int row = rt * 16 + lg * 4 + j;
      const float mu = smu[row], rs = srs[row];
      const int sw = ((row >> 3) & 1) << 4;      // flip 16-bf16 block on odd row-octets
#pragma unroll
      for (int ct = 0; ct < 2; ++ct) {
        float xc = (accC[rt][ct][j] - mu) * rs * gv[ct] + bv[ct];
        xc = fmaxf(xc, 0.f) + accR[rt][ct][j] + rb[ct];
        const int col = w * 32 + ct * 16 + l15;
        As2[row * AS2_STRIDE + (col ^ sw)] = f2u(xc);
      }
    }
  __syncthreads();

  // ---- phase 3: GCN GEMM from As2 (reads apply the same XOR) ----
  uint4 Bg[2][4];
#pragma unroll
  for (int ct = 0; ct < 2; ++ct)
#pragma unroll
    for (int ks = 0; ks < 4; ++ks) Bg[ct][ks] = Bf4[4096 + (ks * 8 + (w * 2 + ct)) * 64 + lane];

  f32x4 acc[8][2];
#pragma unroll
  for (int rt = 0; rt < 8; ++rt)
#pragma unroll
    for (int ct = 0; ct < 2; ++ct) acc[rt][ct] = (f32x4)0.f;

  const int swr = ((l15 >> 3) & 1) << 4;         // row = rt*16+l15 -> (row>>3)&1 = l15>>3
#pragma unroll
  for (int ks = 0; ks < 4; ++ks) {
    bf16x8 af[8];
    const int koff = (ks * 32 + lg * 8) ^ swr;
#pragma unroll
    for (int rt = 0; rt < 8; ++rt)
      af[rt] = *(const bf16x8*)&As2[(rt * 16 + l15) * AS2_STRIDE + koff];
#pragma unroll
    for (int rt = 0; rt < 8; ++rt)
#pragma unroll
      for (int ct = 0; ct < 2; ++ct)
        acc[rt][ct] = MFMA16(af[rt], __builtin_bit_cast(bf16x8, Bg[ct][ks]), acc[rt][ct]);
  }

  // ---- per-node |max| via shfl butterfly (NO LDS atomics; r12/13 lesson) ----
#pragma unroll
  for (int rt = 0; rt < 8; ++rt) {
    float m = 0.f;
#pragma unroll
    for (int ct = 0; ct < 2; ++ct)
#pragma unroll
      for (int j = 0; j < 4; ++j) m = fmaxf(m, fabsf(acc[rt][ct][j]));
    // lanes 0-31 hold node rt*2, lanes 32-63 hold rt*2+1; butterfly stays in-half for d<32
#pragma unroll
    for (int d = 1; d < 32; d <<= 1) m = fmaxf(m, __shfl_xor(m, d, 64));
    if ((lane & 31) == 0) pmax4[w][rt * 2 + (lane >> 5)] = m;
  }
  __syncthreads();
  if (tid < 16) {
    const float mx = fmaxf(fmaxf(pmax4[0][tid], pmax4[1][tid]), fmaxf(pmax4[2][tid], pmax4[3][tid]));
    smax16[tid] = mx;
    qsc[n0 + tid] = mx * (1.f / 127.f);
  }
  __syncthreads();

  // ---- store xq only: row128 = rt*16+lg*4+j -> nn = rt*2+(lg>>1), t = (lg&1)*4 + j ----
  const int t0 = (lg & 1) * 4;
#pragma unroll
  for (int rt = 0; rt < 8; ++rt) {
    const int nn = rt * 2 + (lg >> 1);
    const size_t n = (size_t)(n0 + nn);
    const float mx = smax16[nn];
    const float inv = (mx > 0.f) ? 127.f / mx : 0.f;
#pragma unroll
    for (int ct = 0; ct < 2; ++ct) {
      const int col = w * 32 + ct * 16 + l15;
      unsigned int pk8 = 0;
#pragma unroll
      for (int j = 0; j < 4; ++j) {
        const int q = (int)rintf(acc[rt][ct][j] * inv) + 128;  // biased uint8
        pk8 |= ((unsigned int)q) << (8 * j);
      }
      *(unsigned int*)(xq + (n * C_OUT + col) * T_STEPS + t0) = pk8;
    }
  }
}

// ---------------- CSR aggregation + bias + ReLU -> out[T,N,128] ----------------
// one wave per destination; ALL terms (incl. self) from int8 xq with -128 bias correction
__global__ __launch_bounds__(256) void k_agg(const unsigned char* __restrict__ xq,
                                             const float* __restrict__ qsc,
                                             const uint2* __restrict__ srcnrm,
                                             const int* __restrict__ off, const float* __restrict__ dinv,
                                             const float* __restrict__ gcn_b, float* __restrict__ out) {
  const int tid = threadIdx.x, lane = tid & 63, w = tid >> 6;
  const int j = blockIdx.x * 4 + w;             // grid 5000 exact
  const int s = off[j], e = off[j + 1];
  const float d2 = dinv[j] * dinv[j];

  float acc[2][8];
#pragma unroll
  for (int h = 0; h < 2; ++h)
#pragma unroll
    for (int t = 0; t < 8; ++t) acc[h][t] = 0.f;

  float summul;
  {
    // self term as a degenerate edge: mul = d2 * qsc[j]
    const float mul = d2 * qsc[j];
    summul = mul;
    const uint2 qa = *(const uint2*)(xq + ((size_t)j * C_OUT + lane) * T_STEPS);
    const uint2 qb = *(const uint2*)(xq + ((size_t)j * C_OUT + 64 + lane) * T_STEPS);
#pragma unroll
    for (int tt = 0; tt < 4; ++tt) {
      acc[0][tt]     = fmaf((float)((qa.x >> (8 * tt)) & 0xffu), mul, acc[0][tt]);
      acc[0][4 + tt] = fmaf((float)((qa.y >> (8 * tt)) & 0xffu), mul, acc[0][4 + tt]);
      acc[1][tt]     = fmaf((float)((qb.x >> (8 * tt)) & 0xffu), mul, acc[1][tt]);
      acc[1][4 + tt] = fmaf((float)((qb.y >> (8 * tt)) & 0xffu), mul, acc[1][4 + tt]);
    }
  }

  for (int k = s; k < e; ++k) {
    const uint2 sn = srcnrm[k];                  // wave-uniform
    const int r = (int)sn.x;
    const float mul = __builtin_bit_cast(float, sn.y) * qsc[r];
    summul += mul;
    const uint2 qa = *(const uint2*)(xq + ((size_t)r * C_OUT + lane) * T_STEPS);
    const uint2 qb = *(const uint2*)(xq + ((size_t)r * C_OUT + 64 + lane) * T_STEPS);
#pragma unroll
    for (int tt = 0; tt < 4; ++tt) {
      acc[0][tt]     = fmaf((float)((qa.x >> (8 * tt)) & 0xffu), mul, acc[0][tt]);
      acc[0][4 + tt] = fmaf((float)((qa.y >> (8 * tt)) & 0xffu), mul, acc[0][4 + tt]);
      acc[1][tt]     = fmaf((float)((qb.x >> (8 * tt)) & 0xffu), mul, acc[1][tt]);
      acc[1][4 + tt] = fmaf((float)((qb.y >> (8 * tt)) & 0xffu), mul, acc[1][4 + tt]);
    }
  }

  const float corr = 128.f * summul;             // biased-uint8 correction (incl. self)
  const float b0 = gcn_b[lane], b1 = gcn_b[64 + lane];
#pragma unroll
  for (int h = 0; h < 2; ++h) {
    const float bo = h ? b1 : b0;
#pragma unroll
    for (int t = 0; t < 8; ++t) {
      const float v = acc[h][t] - corr + bo;
      out[((size_t)t * N_NODES + j) * C_OUT + h * 64 + lane] = fmaxf(v, 0.f);
    }
  }
}

// ---------------- host ----------------
extern "C" void kernel_launch(void* const* d_in, const int* in_sizes, int n_in,
                              void* d_out, int out_size, void* d_ws, size_t ws_size,
                              hipStream_t stream) {
  (void)in_sizes; (void)n_in; (void)out_size; (void)ws_size;
  const float* x       = (const float*)d_in[0];
  const int*   ei      = (const int*)d_in[1];
  const float* ewt     = (const float*)d_in[2];
  const float* tconv_w = (const float*)d_in[3];
  const float* tconv_b = (const float*)d_in[4];
  const float* ln_g    = (const float*)d_in[5];
  const float* ln_b    = (const float*)d_in[6];
  const float* res_w   = (const float*)d_in[7];
  const float* res_b   = (const float*)d_in[8];
  const float* gcn_w   = (const float*)d_in[9];
  const float* gcn_b   = (const float*)d_in[10];
  float* out = (float*)d_out;

  // workspace carve (~24 MB)
  unsigned char* xq = (unsigned char*)d_ws;                         // N*128*8 u8 = 20.48 MB
  float* qsc  = (float*)(xq + (size_t)N_NODES * C_OUT * T_STEPS);   // N
  unsigned int* Bf = (unsigned int*)(qsc + N_NODES);                // 24576 u32
  float* ewv   = (float*)(Bf + 24576);                              // E
  float* deg   = ewv + E_EDGES;                                     // N
  float* dinv  = deg + N_NODES;                                     // N
  float* pm    = dinv + N_NODES;                                    // 256
  float* ps    = pm + 256;                                          // 256
  int*   cnt    = (int*)(ps + 256);                                 // N
  int*   off    = cnt + N_NODES;                                    // N+1
  int*   cursor = off + N_NODES + 1;                                // N
  int*   csum   = cursor + N_NODES;                                 // 128
  uint2* srcnrm = (uint2*)(((size_t)(csum + 128) + 15) & ~(size_t)15);  // E * 8B

  const int nblk = (N_NODES + 255) / 256;                           // 79
  const int eblk = E_EDGES / 256;                                   // 625 exact

  k_wprep<<<96, 256, 0, stream>>>(tconv_w, res_w, gcn_w, Bf, deg, cnt);
  k_esoft<<<256, 256, 0, stream>>>(ewt, pm, ps);
  k_edge<<<eblk, 256, 0, stream>>>(ewt, ei, pm, ps, ewv, deg, cnt);
  k_scanA<<<nblk, 256, 0, stream>>>(cnt, deg, dinv, csum);
  k_scanC<<<nblk, 256, 0, stream>>>(cnt, csum, off, cursor);
  k_norm_scatter<<<eblk, 256, 0, stream>>>(ei, ewv, dinv, cursor, srcnrm);

  k_fuse<<<1250, 256, 0, stream>>>(x, tconv_b, ln_g, ln_b, res_b, Bf, xq, qsc);
  k_agg<<<N_NODES / 4, 256, 0, stream>>>(xq, qsc, srcnrm, off, dinv, gcn_b, out);
}